// Round 2
// baseline (1405.017 us; speedup 1.0000x reference)
//
#include <hip/hip_runtime.h>
#include <math.h>

#define LQ 2048
#define DM 1024
#define NH 16
#define DH 64
#define UU 38
#define NBH 64            // B*NH = 4*16
#define SCALE 0.125f      // 1/sqrt(64)

// workspace layout:
//   [0 .. 1MB)    lsum  : 131072 doubles
//   [1MB .. 2MB)  tsum  : 131072 doubles
//   [2MB ..)      sel   : 64*38 ints, l3: 64*38 floats, acc: 64*38*64 floats
#define WS_DBL (2 * 131072)
#define WS_TAIL_FLOATS (2432 + 2432 + 155648)
#define WS_BYTES (WS_DBL * 8 + WS_TAIL_FLOATS * 4)

// ---------------------------------------------------------------------------
// Kernel 1: streaming KL partials. One thread = one query; K tiles in LDS read
// at wave-uniform addresses (broadcast, conflict-free). Dot products in fp32;
// the 2048-term l = sum(e^s) and t = sum(s*e^s) accumulate in FP64 so the KL
// ordering noise (~1e-7) sits far below numpy's (~1e-6) and the rank gaps
// (~1e-3). K-split x2; partials combined with f64 atomicAdd (2 commutative
// adders -> deterministic).
// ---------------------------------------------------------------------------
__global__ __launch_bounds__(256) void kl_partial(const float* __restrict__ Q,
                                                  const float* __restrict__ K,
                                                  double* __restrict__ lsum,
                                                  double* __restrict__ tsum) {
  int blk = blockIdx.x;
  int split = blk & 1;
  blk >>= 1;
  int qt = blk & 7;
  int bh = blk >> 3;
  int b = bh >> 4, h = bh & 15;
  int t = threadIdx.x;
  int q = qt * 256 + t;

  const float4* qp = (const float4*)(Q + ((size_t)(b * LQ + q)) * DM + h * DH);
  float4 qv[16];
#pragma unroll
  for (int i = 0; i < 16; ++i) qv[i] = qp[i];

  __shared__ float4 kt[128 * 16];   // 128 keys x 64 floats = 32 KB
  double l = 0.0, ts = 0.0;
  int kbase = split * 1024;

  for (int k0 = 0; k0 < 1024; k0 += 128) {
    __syncthreads();
#pragma unroll
    for (int i = 0; i < 8; ++i) {
      int idx = i * 256 + t;
      int kk = idx >> 4, d4 = idx & 15;
      kt[idx] = ((const float4*)(K + ((size_t)(b * LQ + kbase + k0 + kk)) * DM + h * DH))[d4];
    }
    __syncthreads();
    for (int j = 0; j < 128; ++j) {
      const float4* krow = &kt[j * 16];
      float4 a = make_float4(0.f, 0.f, 0.f, 0.f);
      float4 c = make_float4(0.f, 0.f, 0.f, 0.f);
#pragma unroll
      for (int d4 = 0; d4 < 16; d4 += 2) {
        float4 k0v = krow[d4];
        float4 k1v = krow[d4 + 1];
        a.x = fmaf(qv[d4].x, k0v.x, a.x);
        a.y = fmaf(qv[d4].y, k0v.y, a.y);
        a.z = fmaf(qv[d4].z, k0v.z, a.z);
        a.w = fmaf(qv[d4].w, k0v.w, a.w);
        c.x = fmaf(qv[d4 + 1].x, k1v.x, c.x);
        c.y = fmaf(qv[d4 + 1].y, k1v.y, c.y);
        c.z = fmaf(qv[d4 + 1].z, k1v.z, c.z);
        c.w = fmaf(qv[d4 + 1].w, k1v.w, c.w);
      }
      float s = ((a.x + a.y) + (a.z + a.w)) + ((c.x + c.y) + (c.z + c.w));
      s *= SCALE;
      float e = __expf(s);
      double ed = (double)e;
      l += ed;
      ts = fma((double)s, ed, ts);
    }
  }
  atomicAdd(&lsum[(size_t)bh * LQ + q], l);
  atomicAdd(&tsum[(size_t)bh * LQ + q], ts);
}

// ---------------------------------------------------------------------------
// Kernel 2: per-(b,h) top-38 by KL (fp64 compare), descending, ties -> lower
// index. Iterative argmax over an LDS copy.
// ---------------------------------------------------------------------------
__global__ __launch_bounds__(256) void topk_kernel(const double* __restrict__ lsum,
                                                   const double* __restrict__ tsum,
                                                   int* __restrict__ idxout) {
  int bh = blockIdx.x;
  int t = threadIdx.x;
  __shared__ double vals[LQ];      // 16 KB
  __shared__ double bv[4];
  __shared__ int bi[4];
  const double logL = 7.624618986159398;  // ln(2048)
  for (int i = t; i < LQ; i += 256) {
    double l = lsum[(size_t)bh * LQ + i];
    double s = tsum[(size_t)bh * LQ + i];
    vals[i] = s / l - log(l) + logL;
  }
  __syncthreads();
  for (int u = 0; u < UU; ++u) {
    double best = -INFINITY;
    int besti = LQ;
    for (int i = t; i < LQ; i += 256) {
      double v = vals[i];
      if (v > best) { best = v; besti = i; }
    }
#pragma unroll
    for (int off = 32; off > 0; off >>= 1) {
      double ov = __shfl_down(best, off);
      int oi = __shfl_down(besti, off);
      if (ov > best || (ov == best && oi < besti)) { best = ov; besti = oi; }
    }
    if ((t & 63) == 0) { bv[t >> 6] = best; bi[t >> 6] = besti; }
    __syncthreads();
    if (t == 0) {
      double fb = bv[0]; int fi = bi[0];
      for (int w2 = 1; w2 < 4; ++w2) {
        if (bv[w2] > fb || (bv[w2] == fb && bi[w2] < fi)) { fb = bv[w2]; fi = bi[w2]; }
      }
      idxout[bh * UU + u] = fi;
      vals[fi] = -INFINITY;
    }
    __syncthreads();
  }
}

// ---------------------------------------------------------------------------
// Kernel 3: sparse attention. grid = (b,h) x 4 key-blocks of 512 keys.
// lane = selected-query u (38 active of 64); waves split the keys of a tile.
// Unnormalized e^s -> weights output (via padded LDS transpose buffer for
// coalescing); denominators and P*V partials via global atomics.
// ---------------------------------------------------------------------------
__global__ __launch_bounds__(256) void attn_kernel(const float* __restrict__ Q,
                                                   const float* __restrict__ K,
                                                   const float* __restrict__ V,
                                                   const int* __restrict__ sel,
                                                   float* __restrict__ wout,
                                                   float* __restrict__ l3,
                                                   float* __restrict__ acc) {
  int bh = blockIdx.x >> 2;
  int kb = blockIdx.x & 3;
  int b = bh >> 4, h = bh & 15;
  int t = threadIdx.x;
  int lane = t & 63, w = t >> 6;

  __shared__ float4 kt[128 * 16];   // 32 KB
  __shared__ float4 vt[128 * 16];   // 32 KB
  __shared__ float qs[UU * 68];
  __shared__ float els[UU * 129];
  __shared__ int sidx[UU];

  if (t < UU) sidx[t] = sel[bh * UU + t];
  __syncthreads();
  for (int i = t; i < UU * DH; i += 256) {
    int u = i >> 6, d = i & 63;
    qs[u * 68 + d] = Q[((size_t)(b * LQ + sidx[u])) * DM + h * DH + d];
  }
  __syncthreads();

  bool act = lane < UU;
  float4 qv[16];
  if (act) {
    const float4* qp = (const float4*)(qs + lane * 68);
#pragma unroll
    for (int i = 0; i < 16; ++i) qv[i] = qp[i];
  } else {
#pragma unroll
    for (int i = 0; i < 16; ++i) qv[i] = make_float4(0.f, 0.f, 0.f, 0.f);
  }

  float l_acc = 0.f;
  float4 o[16];
#pragma unroll
  for (int i = 0; i < 16; ++i) o[i] = make_float4(0.f, 0.f, 0.f, 0.f);

  for (int tile = 0; tile < 4; ++tile) {
    int k0 = kb * 512 + tile * 128;
    __syncthreads();
#pragma unroll
    for (int i = 0; i < 8; ++i) {
      int idx = i * 256 + t;
      int kk = idx >> 4, d4 = idx & 15;
      size_t roff = ((size_t)(b * LQ + k0 + kk)) * DM + h * DH;
      kt[idx] = ((const float4*)(K + roff))[d4];
      vt[idx] = ((const float4*)(V + roff))[d4];
    }
    __syncthreads();
    for (int jj = 0; jj < 32; ++jj) {
      int j = w * 32 + jj;
      const float4* krow = &kt[j * 16];
      float4 a = make_float4(0.f, 0.f, 0.f, 0.f);
      float4 c = make_float4(0.f, 0.f, 0.f, 0.f);
#pragma unroll
      for (int d4 = 0; d4 < 16; d4 += 2) {
        float4 k0v = krow[d4];
        float4 k1v = krow[d4 + 1];
        a.x = fmaf(qv[d4].x, k0v.x, a.x);
        a.y = fmaf(qv[d4].y, k0v.y, a.y);
        a.z = fmaf(qv[d4].z, k0v.z, a.z);
        a.w = fmaf(qv[d4].w, k0v.w, a.w);
        c.x = fmaf(qv[d4 + 1].x, k1v.x, c.x);
        c.y = fmaf(qv[d4 + 1].y, k1v.y, c.y);
        c.z = fmaf(qv[d4 + 1].z, k1v.z, c.z);
        c.w = fmaf(qv[d4 + 1].w, k1v.w, c.w);
      }
      float s = (((a.x + a.y) + (a.z + a.w)) + ((c.x + c.y) + (c.z + c.w))) * SCALE;
      float e = act ? __expf(s) : 0.f;
      if (act) els[lane * 129 + j] = e;
      l_acc += e;
      const float4* vrow = &vt[j * 16];
#pragma unroll
      for (int d4 = 0; d4 < 16; ++d4) {
        float4 vv = vrow[d4];
        o[d4].x = fmaf(e, vv.x, o[d4].x);
        o[d4].y = fmaf(e, vv.y, o[d4].y);
        o[d4].z = fmaf(e, vv.z, o[d4].z);
        o[d4].w = fmaf(e, vv.w, o[d4].w);
      }
    }
    __syncthreads();
    for (int i = t; i < UU * 128; i += 256) {
      int u2 = i >> 7, j2 = i & 127;
      wout[((size_t)(bh * UU + u2)) * LQ + k0 + j2] = els[u2 * 129 + j2];
    }
  }

  if (act) {
    atomicAdd(&l3[bh * UU + lane], l_acc);
    float* ap = acc + ((size_t)(bh * UU + lane)) * DH;
#pragma unroll
    for (int d4 = 0; d4 < 16; ++d4) {
      atomicAdd(ap + d4 * 4 + 0, o[d4].x);
      atomicAdd(ap + d4 * 4 + 1, o[d4].y);
      atomicAdd(ap + d4 * 4 + 2, o[d4].z);
      atomicAdd(ap + d4 * 4 + 3, o[d4].w);
    }
  }
}

// ---------------------------------------------------------------------------
// Kernel 4: normalize weights in place; scatter normalized P*V rows into the
// (pre-zeroed) dense output.
// ---------------------------------------------------------------------------
__global__ __launch_bounds__(256) void finalize_kernel(const int* __restrict__ sel,
                                                       const float* __restrict__ l3,
                                                       const float* __restrict__ acc,
                                                       float* __restrict__ out,
                                                       float* __restrict__ wout) {
  const int N1 = NBH * UU * LQ;
  const int N2 = NBH * UU * DH;
  int i = blockIdx.x * 256 + threadIdx.x;
  if (i < N1) {
    int bhu = i >> 11;
    wout[i] = wout[i] / l3[bhu];
  } else {
    int i2 = i - N1;
    if (i2 < N2) {
      int bhu = i2 >> 6, d = i2 & 63;
      int bh = bhu / UU;
      int b = bh >> 4, h = bh & 15;
      int q = sel[bhu];
      out[((size_t)(b * LQ + q)) * DM + h * DH + d] = acc[i2] / l3[bhu];
    }
  }
}

extern "C" void kernel_launch(void* const* d_in, const int* in_sizes, int n_in,
                              void* d_out, int out_size, void* d_ws, size_t ws_size,
                              hipStream_t stream) {
  (void)in_sizes; (void)n_in; (void)ws_size;
  const float* Q = (const float*)d_in[0];
  const float* K = (const float*)d_in[1];
  const float* V = (const float*)d_in[2];
  float* out = (float*)d_out;
  float* wout = out + (size_t)4 * LQ * DM;  // weights follow the dense output
  double* dws = (double*)d_ws;
  double* lsum = dws;
  double* tsum = dws + 131072;
  float* fws = (float*)(dws + WS_DBL);
  int* sel = (int*)fws;
  float* l3 = fws + 2432;
  float* acc = fws + 4864;

  hipMemsetAsync(out, 0, (size_t)4 * LQ * DM * sizeof(float), stream);
  hipMemsetAsync(d_ws, 0, (size_t)WS_BYTES, stream);

  kl_partial<<<1024, 256, 0, stream>>>(Q, K, lsum, tsum);
  topk_kernel<<<NBH, 256, 0, stream>>>(lsum, tsum, sel);
  attn_kernel<<<NBH * 4, 256, 0, stream>>>(Q, K, V, sel, wout, l3, acc);
  finalize_kernel<<<(NBH * UU * LQ + NBH * UU * DH + 255) / 256, 256, 0, stream>>>(
      sel, l3, acc, out, wout);
}

// Round 3
// 508.779 us; speedup vs baseline: 2.7615x; 2.7615x over previous
//
#include <hip/hip_runtime.h>
#include <math.h>

#define LQ 2048
#define DM 1024
#define NH 16
#define DH 64
#define UU 38
#define NBH 64            // B*NH = 4*16
#define SCALE 0.125f      // 1/sqrt(64)

typedef _Float16 f16x8 __attribute__((ext_vector_type(8)));
typedef _Float16 f16x4 __attribute__((ext_vector_type(4)));
typedef float f32x4 __attribute__((ext_vector_type(4)));

// workspace layout (bytes):
//   [0, 1MB)          vals : 131072 doubles (KL per query)
//   [1MB, +9728)      sel  : 64*38 ints
//   [+9728, +19456)   l3   : 64*38 floats
//   [+19456, +642048) acc  : 64*38*64 floats
#define WS_BYTES (1048576 + 19456 + 622592)

// ---------------------------------------------------------------------------
// Kernel 1: KL via fp16-split MFMA. Block = 4 waves, 128 queries x all 2048
// keys of one (b,h). Scores s = q.k built from 6 mfma_f32_16x16x32_f16 per
// 16x16 tile: hi*hi + hi*lo + lo*hi (fp16 Markidis split; residual ~2^-22,
// products exact in fp32 -> score error ~1e-6 ~= numpy's own fp32 noise).
// l = sum e^s, t = sum s*e^s accumulate fp32 within a 64-key chunk, fold to
// f64 per chunk. KL stored f64, no atomics.
// A-frag layout (16x16x32): A[m=lane&15][k=quad*8+j]; B same; C/D:
// col=lane&15, row=quad*4+reg (learn_hip m89/m120, HW-verified).
// ---------------------------------------------------------------------------
__global__ __launch_bounds__(256) void kl_mfma(const float* __restrict__ Q,
                                               const float* __restrict__ K,
                                               double* __restrict__ vals) {
  int bh = blockIdx.x & 63;     // same-bh blocks land 64 apart -> same XCD (L2 reuse of K)
  int qc = blockIdx.x >> 6;     // 16 query-chunks of 128
  int b = bh >> 4, h = bh & 15;
  int t = threadIdx.x;
  int lane = t & 63, w = t >> 6;
  int quad = lane >> 4, l15 = lane & 15;

  // union: Q stage (128 x 68 fp32 = 34816 B) then Khi/Klo (64 x 88 halves x2 = 22528 B)
  __shared__ __align__(16) char smem[34816];
  float* qs = (float*)smem;

#pragma unroll
  for (int i = 0; i < 8; ++i) {
    int idx = i * 256 + t;
    int row = idx >> 4, d4 = idx & 15;
    float4 v = *(const float4*)(Q + ((size_t)(b * LQ + qc * 128 + row)) * DM + h * DH + d4 * 4);
    *(float4*)(qs + row * 68 + d4 * 4) = v;
  }
  __syncthreads();

  f16x8 ahi[2][2], alo[2][2];
#pragma unroll
  for (int qt = 0; qt < 2; ++qt)
#pragma unroll
    for (int c = 0; c < 2; ++c) {
      const float* p = qs + (w * 32 + qt * 16 + l15) * 68 + c * 32 + quad * 8;
      f16x8 hi, lo;
#pragma unroll
      for (int j = 0; j < 8; ++j) {
        float x = p[j];
        _Float16 hh = (_Float16)x;
        hi[j] = hh;
        lo[j] = (_Float16)(x - (float)hh);
      }
      ahi[qt][c] = hi;
      alo[qt][c] = lo;
    }
  __syncthreads();

  _Float16* khi = (_Float16*)smem;        // [64][88]
  _Float16* klo = khi + 64 * 88;

  double l64[2][4], t64[2][4];
#pragma unroll
  for (int qt = 0; qt < 2; ++qt)
#pragma unroll
    for (int r = 0; r < 4; ++r) { l64[qt][r] = 0.0; t64[qt][r] = 0.0; }

  for (int kb = 0; kb < LQ; kb += 64) {
    __syncthreads();
#pragma unroll
    for (int i = 0; i < 4; ++i) {
      int idx = i * 256 + t;
      int key = idx >> 4, d4 = idx & 15;
      float4 v = *(const float4*)(K + ((size_t)(b * LQ + kb + key)) * DM + h * DH + d4 * 4);
      f16x4 hv, lv;
      hv[0] = (_Float16)v.x; lv[0] = (_Float16)(v.x - (float)hv[0]);
      hv[1] = (_Float16)v.y; lv[1] = (_Float16)(v.y - (float)hv[1]);
      hv[2] = (_Float16)v.z; lv[2] = (_Float16)(v.z - (float)hv[2]);
      hv[3] = (_Float16)v.w; lv[3] = (_Float16)(v.w - (float)hv[3]);
      *(f16x4*)(khi + key * 88 + d4 * 4) = hv;
      *(f16x4*)(klo + key * 88 + d4 * 4) = lv;
    }
    __syncthreads();

    float l32[2][4], t32[2][4];
#pragma unroll
    for (int qt = 0; qt < 2; ++qt)
#pragma unroll
      for (int r = 0; r < 4; ++r) { l32[qt][r] = 0.f; t32[qt][r] = 0.f; }

#pragma unroll
    for (int kt = 0; kt < 4; ++kt) {
      const _Float16* bp = khi + (kt * 16 + l15) * 88 + quad * 8;
      const _Float16* bp2 = klo + (kt * 16 + l15) * 88 + quad * 8;
      f16x8 bhi0 = *(const f16x8*)bp;
      f16x8 bhi1 = *(const f16x8*)(bp + 32);
      f16x8 blo0 = *(const f16x8*)bp2;
      f16x8 blo1 = *(const f16x8*)(bp2 + 32);
#pragma unroll
      for (int qt = 0; qt < 2; ++qt) {
        f32x4 cacc = {0.f, 0.f, 0.f, 0.f};
        // small terms first to keep fp32 accumulation rounding low
        cacc = __builtin_amdgcn_mfma_f32_16x16x32_f16(alo[qt][0], bhi0, cacc, 0, 0, 0);
        cacc = __builtin_amdgcn_mfma_f32_16x16x32_f16(alo[qt][1], bhi1, cacc, 0, 0, 0);
        cacc = __builtin_amdgcn_mfma_f32_16x16x32_f16(ahi[qt][0], blo0, cacc, 0, 0, 0);
        cacc = __builtin_amdgcn_mfma_f32_16x16x32_f16(ahi[qt][1], blo1, cacc, 0, 0, 0);
        cacc = __builtin_amdgcn_mfma_f32_16x16x32_f16(ahi[qt][0], bhi0, cacc, 0, 0, 0);
        cacc = __builtin_amdgcn_mfma_f32_16x16x32_f16(ahi[qt][1], bhi1, cacc, 0, 0, 0);
#pragma unroll
        for (int r = 0; r < 4; ++r) {
          float s = cacc[r] * SCALE;
          float e = __expf(s);
          l32[qt][r] += e;
          t32[qt][r] = fmaf(s, e, t32[qt][r]);
        }
      }
    }
#pragma unroll
    for (int qt = 0; qt < 2; ++qt)
#pragma unroll
      for (int r = 0; r < 4; ++r) {
        l64[qt][r] += (double)l32[qt][r];
        t64[qt][r] += (double)t32[qt][r];
      }
  }

  // reduce across the 16 lanes of each quad-group (cols), then store KL
#pragma unroll
  for (int qt = 0; qt < 2; ++qt)
#pragma unroll
    for (int r = 0; r < 4; ++r) {
      double lv = l64[qt][r], tv = t64[qt][r];
#pragma unroll
      for (int m = 1; m < 16; m <<= 1) {
        lv += __shfl_xor(lv, m);
        tv += __shfl_xor(tv, m);
      }
      if (l15 == 0) {
        int qg = qc * 128 + w * 32 + qt * 16 + quad * 4 + r;
        vals[(size_t)bh * LQ + qg] = tv / lv - log(lv) + 7.624618986159398;
      }
    }
}

// ---------------------------------------------------------------------------
// Kernel 2: per-(b,h) top-38 by KL (fp64), descending, ties -> lower index.
// ---------------------------------------------------------------------------
__global__ __launch_bounds__(256) void topk_kernel(const double* __restrict__ vals_in,
                                                   int* __restrict__ idxout) {
  int bh = blockIdx.x;
  int t = threadIdx.x;
  __shared__ double vals[LQ];      // 16 KB
  __shared__ double bv[4];
  __shared__ int bi[4];
  for (int i = t; i < LQ; i += 256) vals[i] = vals_in[(size_t)bh * LQ + i];
  __syncthreads();
  for (int u = 0; u < UU; ++u) {
    double best = -INFINITY;
    int besti = LQ;
    for (int i = t; i < LQ; i += 256) {
      double v = vals[i];
      if (v > best) { best = v; besti = i; }
    }
#pragma unroll
    for (int off = 32; off > 0; off >>= 1) {
      double ov = __shfl_down(best, off);
      int oi = __shfl_down(besti, off);
      if (ov > best || (ov == best && oi < besti)) { best = ov; besti = oi; }
    }
    if ((t & 63) == 0) { bv[t >> 6] = best; bi[t >> 6] = besti; }
    __syncthreads();
    if (t == 0) {
      double fb = bv[0]; int fi = bi[0];
      for (int w2 = 1; w2 < 4; ++w2) {
        if (bv[w2] > fb || (bv[w2] == fb && bi[w2] < fi)) { fb = bv[w2]; fi = bi[w2]; }
      }
      idxout[bh * UU + u] = fi;
      vals[fi] = -INFINITY;
    }
    __syncthreads();
  }
}

// ---------------------------------------------------------------------------
// Kernel 3: sparse attention (38 queries x 2048 keys per (b,h)).
// ---------------------------------------------------------------------------
__global__ __launch_bounds__(256) void attn_kernel(const float* __restrict__ Q,
                                                   const float* __restrict__ K,
                                                   const float* __restrict__ V,
                                                   const int* __restrict__ sel,
                                                   float* __restrict__ wout,
                                                   float* __restrict__ l3,
                                                   float* __restrict__ acc) {
  int bh = blockIdx.x >> 2;
  int kb = blockIdx.x & 3;
  int b = bh >> 4, h = bh & 15;
  int t = threadIdx.x;
  int lane = t & 63, w = t >> 6;

  __shared__ float4 kt[128 * 16];   // 32 KB
  __shared__ float4 vt[128 * 16];   // 32 KB
  __shared__ float qs[UU * 68];
  __shared__ float els[UU * 129];
  __shared__ int sidx[UU];

  if (t < UU) sidx[t] = sel[bh * UU + t];
  __syncthreads();
  for (int i = t; i < UU * DH; i += 256) {
    int u = i >> 6, d = i & 63;
    qs[u * 68 + d] = Q[((size_t)(b * LQ + sidx[u])) * DM + h * DH + d];
  }
  __syncthreads();

  bool act = lane < UU;
  float4 qv[16];
  if (act) {
    const float4* qp = (const float4*)(qs + lane * 68);
#pragma unroll
    for (int i = 0; i < 16; ++i) qv[i] = qp[i];
  } else {
#pragma unroll
    for (int i = 0; i < 16; ++i) qv[i] = make_float4(0.f, 0.f, 0.f, 0.f);
  }

  float l_acc = 0.f;
  float4 o[16];
#pragma unroll
  for (int i = 0; i < 16; ++i) o[i] = make_float4(0.f, 0.f, 0.f, 0.f);

  for (int tile = 0; tile < 4; ++tile) {
    int k0 = kb * 512 + tile * 128;
    __syncthreads();
#pragma unroll
    for (int i = 0; i < 8; ++i) {
      int idx = i * 256 + t;
      int kk = idx >> 4, d4 = idx & 15;
      size_t roff = ((size_t)(b * LQ + k0 + kk)) * DM + h * DH;
      kt[idx] = ((const float4*)(K + roff))[d4];
      vt[idx] = ((const float4*)(V + roff))[d4];
    }
    __syncthreads();
    for (int jj = 0; jj < 32; ++jj) {
      int j = w * 32 + jj;
      const float4* krow = &kt[j * 16];
      float4 a = make_float4(0.f, 0.f, 0.f, 0.f);
      float4 c = make_float4(0.f, 0.f, 0.f, 0.f);
#pragma unroll
      for (int d4 = 0; d4 < 16; d4 += 2) {
        float4 k0v = krow[d4];
        float4 k1v = krow[d4 + 1];
        a.x = fmaf(qv[d4].x, k0v.x, a.x);
        a.y = fmaf(qv[d4].y, k0v.y, a.y);
        a.z = fmaf(qv[d4].z, k0v.z, a.z);
        a.w = fmaf(qv[d4].w, k0v.w, a.w);
        c.x = fmaf(qv[d4 + 1].x, k1v.x, c.x);
        c.y = fmaf(qv[d4 + 1].y, k1v.y, c.y);
        c.z = fmaf(qv[d4 + 1].z, k1v.z, c.z);
        c.w = fmaf(qv[d4 + 1].w, k1v.w, c.w);
      }
      float s = (((a.x + a.y) + (a.z + a.w)) + ((c.x + c.y) + (c.z + c.w))) * SCALE;
      float e = act ? __expf(s) : 0.f;
      if (act) els[lane * 129 + j] = e;
      l_acc += e;
      const float4* vrow = &vt[j * 16];
#pragma unroll
      for (int d4 = 0; d4 < 16; ++d4) {
        float4 vv = vrow[d4];
        o[d4].x = fmaf(e, vv.x, o[d4].x);
        o[d4].y = fmaf(e, vv.y, o[d4].y);
        o[d4].z = fmaf(e, vv.z, o[d4].z);
        o[d4].w = fmaf(e, vv.w, o[d4].w);
      }
    }
    __syncthreads();
    for (int i = t; i < UU * 128; i += 256) {
      int u2 = i >> 7, j2 = i & 127;
      wout[((size_t)(bh * UU + u2)) * LQ + k0 + j2] = els[u2 * 129 + j2];
    }
  }

  if (act) {
    atomicAdd(&l3[bh * UU + lane], l_acc);
    float* ap = acc + ((size_t)(bh * UU + lane)) * DH;
#pragma unroll
    for (int d4 = 0; d4 < 16; ++d4) {
      atomicAdd(ap + d4 * 4 + 0, o[d4].x);
      atomicAdd(ap + d4 * 4 + 1, o[d4].y);
      atomicAdd(ap + d4 * 4 + 2, o[d4].z);
      atomicAdd(ap + d4 * 4 + 3, o[d4].w);
    }
  }
}

// ---------------------------------------------------------------------------
// Kernel 4: normalize weights; scatter normalized P*V into zeroed output.
// ---------------------------------------------------------------------------
__global__ __launch_bounds__(256) void finalize_kernel(const int* __restrict__ sel,
                                                       const float* __restrict__ l3,
                                                       const float* __restrict__ acc,
                                                       float* __restrict__ out,
                                                       float* __restrict__ wout) {
  const int N1 = NBH * UU * LQ;
  const int N2 = NBH * UU * DH;
  int i = blockIdx.x * 256 + threadIdx.x;
  if (i < N1) {
    int bhu = i >> 11;
    wout[i] = wout[i] / l3[bhu];
  } else {
    int i2 = i - N1;
    if (i2 < N2) {
      int bhu = i2 >> 6, d = i2 & 63;
      int bh = bhu / UU;
      int b = bh >> 4, h = bh & 15;
      int q = sel[bhu];
      out[((size_t)(b * LQ + q)) * DM + h * DH + d] = acc[i2] / l3[bhu];
    }
  }
}

extern "C" void kernel_launch(void* const* d_in, const int* in_sizes, int n_in,
                              void* d_out, int out_size, void* d_ws, size_t ws_size,
                              hipStream_t stream) {
  (void)in_sizes; (void)n_in; (void)ws_size;
  const float* Q = (const float*)d_in[0];
  const float* K = (const float*)d_in[1];
  const float* V = (const float*)d_in[2];
  float* out = (float*)d_out;
  float* wout = out + (size_t)4 * LQ * DM;  // weights follow the dense output
  double* vals = (double*)d_ws;
  int* sel = (int*)((char*)d_ws + 1048576);
  float* l3 = (float*)((char*)d_ws + 1048576 + 9728);
  float* acc = (float*)((char*)d_ws + 1048576 + 19456);

  hipMemsetAsync(out, 0, (size_t)4 * LQ * DM * sizeof(float), stream);
  hipMemsetAsync(d_ws, 0, (size_t)WS_BYTES, stream);

  kl_mfma<<<1024, 256, 0, stream>>>(Q, K, vals);
  topk_kernel<<<NBH, 256, 0, stream>>>(vals, sel);
  attn_kernel<<<NBH * 4, 256, 0, stream>>>(Q, K, V, sel, wout, l3, acc);
  finalize_kernel<<<(NBH * UU * LQ + NBH * UU * DH + 255) / 256, 256, 0, stream>>>(
      sel, l3, acc, out, wout);
}